// Round 7
// baseline (291.378 us; speedup 1.0000x reference)
//
#include <hip/hip_runtime.h>
#include <hip/hip_bf16.h>
#include <math.h>

// Problem constants
#define B_    1024
#define S_    256
#define COV_  512
#define H_    128
#define E_    8
#define ES_   7

// ws layout (floats)
#define W_WS_OFF   0                       // [3][1024][8]
#define COVG_OFF   24576                   // [3][1024][128]
#define USAGE_OFF  417792                  // [3][7] padded

#define AT_STRIDE  136                     // 128 k + 8 pad (bf16), row = 272 B (16B aligned)
#define WT_STRIDE  40                      // 32 k + 8 pad (bf16), row = 80 B  (16B aligned)

typedef __attribute__((ext_vector_type(8))) short bf16x8;  // 8 bf16 = 4 VGPRs (MFMA A/B frag)
typedef __attribute__((ext_vector_type(4))) float f32x4;   // MFMA C/D frag

// Fast softplus: 2 HW transcendentals (v_exp_f32 / v_log_f32) + few VALU.
__device__ __forceinline__ float softplus_f(float x) {
    return fmaxf(x, 0.0f) + __logf(1.0f + __expf(-fabsf(x)));
}

// v_cvt_pk_bf16_f32: pack two fp32 -> two bf16 (RNE).
__device__ __forceinline__ unsigned pk2_bf16(float a, float b) {
    __hip_bfloat162 h = __float22bfloat162_rn(make_float2(a, b));
    return *reinterpret_cast<unsigned*>(&h);
}
__device__ __forceinline__ void split_pair(float a, float b, unsigned &hi, unsigned &lo) {
    hi = pk2_bf16(a, b);
    float ha = __uint_as_float(hi << 16);
    float hb = __uint_as_float(hi & 0xffff0000u);
    lo = pk2_bf16(a - ha, b - hb);
}

struct RouterArgs {
    const float* cov;                      // [1024][512]
    const float* Wr1[3];                   // [512][256]
    const float* br1[3];                   // [256]
    const float* Wr2[3];                   // [256][7]
    const float* br2[3];                   // [7]
    const float* Wc[3];                    // [512][128]
    const float* bc[3];                    // [128]
    float* ws;
};

// grid (128, 3), block 768 (12 waves): 8 b's x one layer per block.
// Register-tiled GEMV: thread = (2 adjacent cols, 8 b's, k-quarter).
// Per k4-iter: 4 coalesced float2 weight loads + 8 broadcast ds_read_b128
// (96 LDS-cyc) feed 64 fmaf (128 VALU-cyc) -> VALU-bound by construction.
// (R2 form was LDS-pipe-bound; R6's s_load form was SMEM-latency-serialized:
//  VALUBusy 3.4%, occupancy 4.6% in profile.)
__global__ __launch_bounds__(768) void router_kernel(RouterArgs a) {
    const int l   = blockIdx.y;
    const int b0  = blockIdx.x * 8;
    const int tid = threadIdx.x;

    __shared__ float4 covs[8][COV_ / 4];   // 16 KB  [bb][k4]
    __shared__ float  part[4][3072];       // 48 KB  [ks][bb*384 + c]
    __shared__ float  hr[8][256];          // 8 KB
    __shared__ float  susage[ES_];
    if (tid < ES_) susage[tid] = 0.0f;

    // stage cov[8][512] -> LDS, coalesced float4
    for (int f = tid; f < 1024; f += 768) {
        const int bb = f >> 7, k4 = f & 127;
        covs[bb][k4] = ((const float4*)(a.cov + (size_t)(b0 + bb) * COV_))[k4];
    }
    __syncthreads();

    // Phase A: GEMV, 2 cols x 8 b's x 128 k's per thread
    {
        const int cp = tid % 192;          // col-pair (wave-uniform matrix split at cp=128)
        const int ks = tid / 192;          // k-quarter 0..3 (wave-uniform)
        const int c0 = cp * 2;
        const float* __restrict__ Wp; int rs;
        if (c0 < 256) { Wp = a.Wr1[l] + c0;         rs = 256; }
        else          { Wp = a.Wc[l]  + (c0 - 256); rs = 128; }

        float acc0[8], acc1[8];
        #pragma unroll
        for (int bb = 0; bb < 8; ++bb) { acc0[bb] = 0.f; acc1[bb] = 0.f; }

        const int k4beg = ks * 32, k4end = k4beg + 32;
        #pragma unroll 2
        for (int k4 = k4beg; k4 < k4end; ++k4) {
            float2 w0 = *(const float2*)(Wp + (size_t)(4 * k4 + 0) * rs);
            float2 w1 = *(const float2*)(Wp + (size_t)(4 * k4 + 1) * rs);
            float2 w2 = *(const float2*)(Wp + (size_t)(4 * k4 + 2) * rs);
            float2 w3 = *(const float2*)(Wp + (size_t)(4 * k4 + 3) * rs);
            #pragma unroll
            for (int bb = 0; bb < 8; ++bb) {
                float4 cv = covs[bb][k4];            // broadcast within wave
                acc0[bb] = fmaf(cv.x, w0.x, acc0[bb]);
                acc1[bb] = fmaf(cv.x, w0.y, acc1[bb]);
                acc0[bb] = fmaf(cv.y, w1.x, acc0[bb]);
                acc1[bb] = fmaf(cv.y, w1.y, acc1[bb]);
                acc0[bb] = fmaf(cv.z, w2.x, acc0[bb]);
                acc1[bb] = fmaf(cv.z, w2.y, acc1[bb]);
                acc0[bb] = fmaf(cv.w, w3.x, acc0[bb]);
                acc1[bb] = fmaf(cv.w, w3.y, acc1[bb]);
            }
        }
        #pragma unroll
        for (int bb = 0; bb < 8; ++bb)
            *(float2*)&part[ks][bb * 384 + c0] = make_float2(acc0[bb], acc1[bb]);
    }
    __syncthreads();

    // Reduce k-quarters: thread handles 4 consecutive (bb,c) slots (384%4==0
    // so the quad never crosses a bb boundary).
    {
        const int p0 = tid * 4;
        float4 s = {0.f, 0.f, 0.f, 0.f};
        #pragma unroll
        for (int ks = 0; ks < 4; ++ks) {
            float4 v = *(const float4*)&part[ks][p0];
            s.x += v.x; s.y += v.y; s.z += v.z; s.w += v.w;
        }
        const int bb = p0 / 384;
        const int c  = p0 % 384;
        const float sv[4] = {s.x, s.y, s.z, s.w};
        if (c < 256) {
            #pragma unroll
            for (int q = 0; q < 4; ++q)
                hr[bb][c + q] = fmaxf(sv[q] + a.br1[l][c + q], 0.0f);
        } else {
            #pragma unroll
            for (int q = 0; q < 4; ++q)
                a.ws[COVG_OFF + (size_t)(l * B_ + b0 + bb) * H_ + (c - 256 + q)] = sv[q] + a.bc[l][c - 256 + q];
        }
    }
    __syncthreads();

    // Phase B: router logits + softmax, one wave per b (waves 0..7 of 12)
    {
        const int wave = tid >> 6;
        const int lane = tid & 63;
        if (wave < 8) {
            const int bb = wave;
            const int o = lane >> 3;      // 0..7 (7 invalid)
            const int g = lane & 7;
            float p = 0.0f;
            if (o < ES_) {
                #pragma unroll
                for (int m = 0; m < 32; ++m) {
                    const int k = g * 32 + m;
                    p = fmaf(hr[bb][k], a.Wr2[l][k * ES_ + o], p);
                }
            }
            p += __shfl_xor(p, 1);
            p += __shfl_xor(p, 2);
            p += __shfl_xor(p, 4);
            const float lg = p + ((o < ES_) ? a.br2[l][o] : 0.0f);
            float v[ES_];
            #pragma unroll
            for (int oo = 0; oo < ES_; ++oo) v[oo] = __shfl(lg, oo * 8, 64);
            if (lane == 0) {
                const int b = b0 + bb;
                float mx = v[0];
                #pragma unroll
                for (int oo = 1; oo < ES_; ++oo) mx = fmaxf(mx, v[oo]);
                float ex[ES_]; float s = 0.0f;
                #pragma unroll
                for (int oo = 0; oo < ES_; ++oo) { ex[oo] = __expf(v[oo] - mx); s += ex[oo]; }
                const float inv = 0.7f / s;            // (1-UW) * softmax
                float* wout = a.ws + W_WS_OFF + (size_t)(l * B_ + b) * 8;
                wout[0] = 0.3f;                        // UW/EU
                #pragma unroll
                for (int oo = 0; oo < ES_; ++oo) {
                    const float rwv = ex[oo] * inv;
                    wout[1 + oo] = rwv;
                    atomicAdd(&susage[oo], rwv);       // LDS pre-reduction
                }
            }
        }
    }
    __syncthreads();
    if (tid < ES_) atomicAdd(a.ws + USAGE_OFF + l * ES_ + tid, susage[tid]);
}

struct MainArgs {
    const float* y_t;        // [1024][256]
    const float* y0;         // [1024][256]
    const int*   t;          // [1024]
    const float* emb[3];     // [1001][128]
    const float* W1;         // [8][2][128]
    const float* W2;         // [8][128][128]
    const float* W3;         // [8][128][128]
    const float* b_[3];      // [8][128]
    const float* W4;         // [128]
    const float* b4;         // [1]
    float* ws;
    float* out;              // [1024*256] + [1] load
};

// grid 1024 (one b per block), 1024 threads (16 waves), ~158.5 KB LDS
// -> 1 block/CU, 4 waves/SIMD. Wave tile 32 tok x 64 n. (Unchanged from R6.)
__global__ __launch_bounds__(1024, 4) void main_kernel(MainArgs a) {
    __shared__ unsigned short Ahi[256 * AT_STRIDE];      // 69632 B
    __shared__ unsigned short Alo[256 * AT_STRIDE];      // 69632 B
    __shared__ unsigned short WtBuf[2][128 * WT_STRIDE]; // 20480 B; aliased: L1 coeffs / pos
    __shared__ float GPs[2][128];    // gamma*(1+covg) for layers 2,3
    __shared__ float GPBs[2][128];   // GPs * bmix
    __shared__ float W4s[128];

    const int tid  = threadIdx.x;
    const int b    = blockIdx.x;
    const int lane = tid & 63;
    const int w    = tid >> 6;      // 0..15
    const int wm   = w >> 1;        // 0..7: token block (32)
    const int wn   = w & 1;         // 0..1: n block (64)
    const int nl   = lane & 15;
    const int quad = lane >> 4;
    const int tb   = a.t[b];

    float* L1f = (float*)WtBuf;     // [0:128)=A, [128:256)=B, [256:384)=C coeffs

    // ---- prologue: per-layer modulation vectors ----
    if (tid < 384) {
        const int l = tid >> 7, j = tid & 127;
        const float* wv = a.ws + W_WS_OFF + (size_t)(l * B_ + b) * 8;
        const float gamma = a.emb[l][tb * H_ + j];
        const float covg  = a.ws[COVG_OFF + (size_t)(l * B_ + b) * H_ + j];
        const float gp = gamma * (1.0f + covg);
        const float* bl = a.b_[l];
        float bm = 0.0f;
        #pragma unroll
        for (int e = 0; e < E_; ++e) bm = fmaf(wv[e], bl[e * H_ + j], bm);
        if (l == 0) {
            float s0 = 0.0f, s1 = 0.0f;
            #pragma unroll
            for (int e = 0; e < E_; ++e) {
                s0 = fmaf(wv[e], a.W1[e * 256 + j], s0);
                s1 = fmaf(wv[e], a.W1[e * 256 + 128 + j], s1);
            }
            L1f[j]       = gp * s0;
            L1f[128 + j] = gp * s1;
            L1f[256 + j] = gp * bm;
        } else {
            GPs[l - 1][j]  = gp;
            GPBs[l - 1][j] = gp * bm;
        }
    }
    if (tid < 128) W4s[tid] = a.W4[tid];
    __syncthreads();

    // ---- layer 1 (nin=2): 4 threads per token, write At hi/lo ----
    {
        const int tok = tid >> 2;
        const int jh  = (tid & 3) * 32;
        const float x0 = a.y_t[b * S_ + tok];
        const float x1 = a.y0[b * S_ + tok];
        #pragma unroll
        for (int g = 0; g < 4; ++g) {
            const int jb = jh + g * 8;
            unsigned hp[4], lp[4];
            #pragma unroll
            for (int p = 0; p < 4; ++p) {
                const int j0 = jb + 2 * p;
                float m0 = fmaf(x0, L1f[j0],     fmaf(x1, L1f[128 + j0],     L1f[256 + j0]));
                float m1 = fmaf(x0, L1f[j0 + 1], fmaf(x1, L1f[128 + j0 + 1], L1f[256 + j0 + 1]));
                split_pair(softplus_f(m0), softplus_f(m1), hp[p], lp[p]);
            }
            *(uint4*)&Ahi[tok * AT_STRIDE + jb] = make_uint4(hp[0], hp[1], hp[2], hp[3]);
            *(uint4*)&Alo[tok * AT_STRIDE + jb] = make_uint4(lp[0], lp[1], lp[2], lp[3]);
        }
    }
    // (first chunk barrier below synchronizes At)

    const int bj  = tid & 127;     // Weff-build: column j
    const int bkg = tid >> 7;      // Weff-build: k-group (4 k's), 0..7

    for (int L = 0; L < 2; ++L) {
        const float* __restrict__ Wg = L ? a.W3 : a.W2;
        const float* wv = a.ws + W_WS_OFF + (size_t)((L + 1) * B_ + b) * 8;
        float we[E_];
        #pragma unroll
        for (int e = 0; e < E_; ++e) we[e] = wv[e];

        f32x4 acc[2][4];
        #pragma unroll
        for (int mt = 0; mt < 2; ++mt)
            #pragma unroll
            for (int nt = 0; nt < 4; ++nt)
                acc[mt][nt] = (f32x4){0.f, 0.f, 0.f, 0.f};

        // Weff chunk builder: 4 k's x 1 column per thread
        unsigned bh[2], blo_[2];
        auto build = [&](int kc) {
            float bacc[4] = {0.f, 0.f, 0.f, 0.f};
            const float* base = Wg + (size_t)(kc * 32 + bkg * 4) * H_ + bj;
            #pragma unroll
            for (int e = 0; e < E_; ++e) {
                const float* p = base + (size_t)e * (H_ * H_);
                const float wE = we[e];
                #pragma unroll
                for (int i = 0; i < 4; ++i)
                    bacc[i] = fmaf(wE, p[i * H_], bacc[i]);
            }
            split_pair(bacc[0], bacc[1], bh[0], blo_[0]);
            split_pair(bacc[2], bacc[3], bh[1], blo_[1]);
        };

        build(0);

        for (int kc = 0; kc < 4; ++kc) {
            __syncthreads();   // prev GEMM done reading Wt; At writes visible (kc==0)
            *(uint2*)&WtBuf[0][bj * WT_STRIDE + bkg * 4] = make_uint2(bh[0], bh[1]);
            *(uint2*)&WtBuf[1][bj * WT_STRIDE + bkg * 4] = make_uint2(blo_[0], blo_[1]);
            __syncthreads();

            // GEMM k-step (K=32)
            const int ka = kc * 32 + quad * 8;
            bf16x8 Af[2], Al[2], Bf[4], Bl[4];
            #pragma unroll
            for (int mt = 0; mt < 2; ++mt) {
                const int row = (wm * 32 + mt * 16 + nl) * AT_STRIDE + ka;
                Af[mt] = *(const bf16x8*)&Ahi[row];
                Al[mt] = *(const bf16x8*)&Alo[row];
            }
            #pragma unroll
            for (int nt = 0; nt < 4; ++nt) {
                const int row = (wn * 64 + nt * 16 + nl) * WT_STRIDE + quad * 8;
                Bf[nt] = *(const bf16x8*)&WtBuf[0][row];
                Bl[nt] = *(const bf16x8*)&WtBuf[1][row];
            }
            #pragma unroll
            for (int mt = 0; mt < 2; ++mt)
                #pragma unroll
                for (int nt = 0; nt < 4; ++nt) {
                    acc[mt][nt] = __builtin_amdgcn_mfma_f32_16x16x32_bf16(Af[mt], Bf[nt], acc[mt][nt], 0, 0, 0);
                    acc[mt][nt] = __builtin_amdgcn_mfma_f32_16x16x32_bf16(Af[mt], Bl[nt], acc[mt][nt], 0, 0, 0);
                    acc[mt][nt] = __builtin_amdgcn_mfma_f32_16x16x32_bf16(Al[mt], Bf[nt], acc[mt][nt], 0, 0, 0);
                }

            if (kc < 3) build(kc + 1);
        }
        __syncthreads();   // all GEMM reads of At / Wt done

        if (L == 0) {
            // epilogue layer2 -> At (hi/lo); C layout: n=nl(+16*nt), tok=quad*4+r(+16*mt)
            #pragma unroll
            for (int nt = 0; nt < 4; ++nt) {
                const int n = wn * 64 + nt * 16 + nl;
                const float gp = GPs[0][n], gpb = GPBs[0][n];
                #pragma unroll
                for (int mt = 0; mt < 2; ++mt) {
                    const int tok0 = wm * 32 + mt * 16 + quad * 4;
                    #pragma unroll
                    for (int rp = 0; rp < 2; ++rp) {
                        const float h0 = softplus_f(fmaf(gp, acc[mt][nt][2 * rp],     gpb));
                        const float h1 = softplus_f(fmaf(gp, acc[mt][nt][2 * rp + 1], gpb));
                        unsigned hh, ll;
                        split_pair(h0, h1, hh, ll);
                        const int t0 = tok0 + 2 * rp;
                        Ahi[t0 * AT_STRIDE + n]       = (unsigned short)hh;
                        Ahi[(t0 + 1) * AT_STRIDE + n] = (unsigned short)(hh >> 16);
                        Alo[t0 * AT_STRIDE + n]       = (unsigned short)ll;
                        Alo[(t0 + 1) * AT_STRIDE + n] = (unsigned short)(ll >> 16);
                    }
                }
            }
        } else {
            // epilogue layer3 fused with h3 @ W4
            float po[2][4];
            #pragma unroll
            for (int mt = 0; mt < 2; ++mt)
                #pragma unroll
                for (int r = 0; r < 4; ++r) po[mt][r] = 0.0f;
            #pragma unroll
            for (int nt = 0; nt < 4; ++nt) {
                const int n = wn * 64 + nt * 16 + nl;
                const float gp = GPs[1][n], gpb = GPBs[1][n], w4 = W4s[n];
                #pragma unroll
                for (int mt = 0; mt < 2; ++mt)
                    #pragma unroll
                    for (int r = 0; r < 4; ++r) {
                        const float h = softplus_f(fmaf(gp, acc[mt][nt][r], gpb));
                        po[mt][r] = fmaf(h, w4, po[mt][r]);
                    }
            }
            #pragma unroll
            for (int mt = 0; mt < 2; ++mt)
                #pragma unroll
                for (int r = 0; r < 4; ++r) {
                    po[mt][r] += __shfl_xor(po[mt][r], 1);
                    po[mt][r] += __shfl_xor(po[mt][r], 2);
                    po[mt][r] += __shfl_xor(po[mt][r], 4);
                    po[mt][r] += __shfl_xor(po[mt][r], 8);
                }
            float* pos = (float*)WtBuf;   // Wt free after post-loop barrier
            if (nl == 0) {
                #pragma unroll
                for (int mt = 0; mt < 2; ++mt)
                    #pragma unroll
                    for (int r = 0; r < 4; ++r)
                        pos[(wm * 32 + mt * 16 + quad * 4 + r) * 2 + wn] = po[mt][r];
            }
            __syncthreads();
            if (tid < 256)
                a.out[b * S_ + tid] = pos[2 * tid] + pos[2 * tid + 1] + a.b4[0];
        }
    }

    // load-balance scalar (router completed before this kernel)
    if (b == 0 && tid == 0) {
        float ld = 0.0f;
        for (int l = 0; l < 3; ++l)
            for (int o = 0; o < ES_; ++o) {
                float u = a.ws[USAGE_OFF + l * ES_ + o] * (1.0f / (float)B_);
                float d = u - (1.0f / (float)ES_);
                ld = fmaf(d, d, ld);
            }
        a.out[B_ * S_] = ld * (1.0f / (float)ES_);
    }
}

extern "C" void kernel_launch(void* const* d_in, const int* in_sizes, int n_in,
                              void* d_out, int out_size, void* d_ws, size_t ws_size,
                              hipStream_t stream) {
    (void)in_sizes; (void)n_in; (void)out_size; (void)ws_size;

    RouterArgs ra;
    ra.cov = (const float*)d_in[2];
    ra.ws  = (float*)d_ws;

    MainArgs ma;
    ma.y_t = (const float*)d_in[0];
    ma.y0  = (const float*)d_in[1];
    ma.t   = (const int*)d_in[3];
    for (int l = 0; l < 3; ++l) {
        const int base = 4 + l * 9;
        ma.emb[l] = (const float*)d_in[base + 0];
        ma.b_[l]  = (const float*)d_in[base + 2];
        ra.Wc[l]  = (const float*)d_in[base + 3];
        ra.bc[l]  = (const float*)d_in[base + 4];
        ra.Wr1[l] = (const float*)d_in[base + 5];
        ra.br1[l] = (const float*)d_in[base + 6];
        ra.Wr2[l] = (const float*)d_in[base + 7];
        ra.br2[l] = (const float*)d_in[base + 8];
    }
    ma.W1 = (const float*)d_in[4 + 0 * 9 + 1];
    ma.W2 = (const float*)d_in[4 + 1 * 9 + 1];
    ma.W3 = (const float*)d_in[4 + 2 * 9 + 1];
    ma.W4 = (const float*)d_in[31];
    ma.b4 = (const float*)d_in[32];
    ma.ws  = (float*)d_ws;
    ma.out = (float*)d_out;

    (void)hipMemsetAsync((char*)d_ws + USAGE_OFF * sizeof(float), 0, 24 * sizeof(float), stream);
    router_kernel<<<dim3(128, 3, 1), 768, 0, stream>>>(ra);
    main_kernel<<<dim3(1024, 1, 1), 1024, 0, stream>>>(ma);
}